// Round 5
// baseline (747.310 us; speedup 1.0000x reference)
//
#include <hip/hip_runtime.h>

// ---- types ----
typedef __attribute__((ext_vector_type(4))) float f32x4;
typedef __attribute__((ext_vector_type(8))) __bf16 bf16x8;
typedef __attribute__((address_space(1))) unsigned int gu32;
typedef __attribute__((address_space(3))) unsigned int lu32;

// Problem constants: x (N=32, C=128, T=512, F=32) fp32
#define PN 32
#define PC 128
#define PT 512
#define PF 32

__device__ inline unsigned short f2bf(float x) {
  unsigned int u = __float_as_uint(x);
  return (unsigned short)((u + 0x7FFFu + ((u >> 16) & 1u)) >> 16);
}
__device__ inline unsigned pk2bf(float lo, float hi) {
  return (unsigned)f2bf(lo) | ((unsigned)f2bf(hi) << 16);
}
__device__ inline float bf2f(unsigned short b) {
  return __uint_as_float(((unsigned int)b) << 16);
}

// ===========================================================================
// FUSED kernel: block = (n, tri-tile in {(0,0),(0,64),(64,64)}, f-group of 8).
// 384 blocks, 512 threads (8 waves), wave w handles f = fg*8 + w.
// Per K-step (kt=64): stage x[n][rows][t0:t0+64][fg*8..+8] -> 8 per-f LDS
// tiles [128 rows][64 t] bf16 (16B-block XOR swizzle by row&7, same as the
// round-2-verified gram), then each wave runs the verified MFMA pattern on
// its own tile: acc(RAxRB) + self-products for exact sq. Off-diag tiles
// write the mirror too (Gram symmetric). Output staged through LDS so
// global stores are 32B f-contiguous chunks.
// Dynamic LDS = 128 KiB (staging 8x16KB; epilogue reuses [0,4K) for sq and
// [64K,128K) for the 32x64x8 f32 out-buffer, two halves).
// ===========================================================================
__global__ __launch_bounds__(512) void fused_kernel(const float* __restrict__ x,
                                                    const float* __restrict__ sigma,
                                                    float* __restrict__ out) {
  extern __shared__ char smem[];            // 131072 bytes

  const int bid = blockIdx.x;
  const int sub = bid % 12;                 // 3 tiles x 4 f-groups
  const int n   = bid / 12;
  const int tile = sub % 3;                 // 0:(0,0) 1:(0,64) 2:(64,64)
  const int fg   = sub / 3;                 // 0..3
  const int i0 = (tile == 2) ? 64 : 0;
  const int j0 = (tile == 0) ? 0 : 64;

  const int tid = threadIdx.x;
  const int w = tid >> 6, ln = tid & 63;
  const int lr = ln & 15, lq = ln >> 4;

  f32x4 acc[4][4];
  f32x4 sa[4], sb[4];
  #pragma unroll
  for (int m = 0; m < 4; ++m) {
    sa[m] = (f32x4){0.f, 0.f, 0.f, 0.f};
    sb[m] = (f32x4){0.f, 0.f, 0.f, 0.f};
    #pragma unroll
    for (int q = 0; q < 4; ++q) acc[m][q] = (f32x4){0.f, 0.f, 0.f, 0.f};
  }

  const int fh = ln & 1;                    // which float4-half of the 8 f's
  const int tp = ln >> 1;                   // 0..31 -> t = t0 + 2*tp
  const size_t xbase = (size_t)n * PC * PT * PF;

  for (int ks = 0; ks < 8; ++ks) {
    const int t0 = ks * 64;
    // ---- stage 128 sr-rows (sr<64 -> RA row i0+sr; else RB row j0+sr-64)
    #pragma unroll
    for (int it = 0; it < 16; ++it) {
      int sr = it * 8 + w;
      int gr = (sr < 64) ? (i0 + sr) : (j0 + sr - 64);
      const float* rp = x + xbase + ((size_t)gr * PT + t0 + 2 * tp) * PF + fg * 8 + fh * 4;
      float4 va = *(const float4*)rp;        // t even
      float4 vb = *(const float4*)(rp + PF); // t odd
      int tb = tp >> 2;                      // t-block-of-8
      int ti = (tp & 3) << 1;                // t offset within block (even)
      int swz = ((tb ^ (sr & 7)) << 4) + (ti << 1);
      char* base = smem + (fh * 4) * 16384 + sr * 128 + swz;
      *(unsigned*)(base)             = pk2bf(va.x, vb.x);
      *(unsigned*)(base + 16384)     = pk2bf(va.y, vb.y);
      *(unsigned*)(base + 2 * 16384) = pk2bf(va.z, vb.z);
      *(unsigned*)(base + 3 * 16384) = pk2bf(va.w, vb.w);
    }
    __syncthreads();
    // ---- MFMA on wave's own f-tile
    const char* Lw = smem + w * 16384;
    #pragma unroll
    for (int kk = 0; kk < 64; kk += 32) {
      bf16x8 av[4], bv[4];
      #pragma unroll
      for (int m = 0; m < 4; ++m) {
        int ra = m * 16 + lr;
        av[m] = *(const bf16x8*)(Lw + ra * 128 + ((((kk >> 3) + lq) ^ (ra & 7)) << 4));
        int rb = 64 + m * 16 + lr;
        bv[m] = *(const bf16x8*)(Lw + rb * 128 + ((((kk >> 3) + lq) ^ (rb & 7)) << 4));
      }
      #pragma unroll
      for (int m = 0; m < 4; ++m) {
        sa[m] = __builtin_amdgcn_mfma_f32_16x16x32_bf16(av[m], av[m], sa[m], 0, 0, 0);
        sb[m] = __builtin_amdgcn_mfma_f32_16x16x32_bf16(bv[m], bv[m], sb[m], 0, 0, 0);
        #pragma unroll
        for (int q = 0; q < 4; ++q)
          acc[m][q] = __builtin_amdgcn_mfma_f32_16x16x32_bf16(av[m], bv[q], acc[m][q], 0, 0, 0);
      }
    }
    __syncthreads();
  }

  // ---- sq from self-product diagonals (exact match with acc diag)
  float* sqld = (float*)smem;               // [8 waves][128 rows] f32 = 4 KB
  #pragma unroll
  for (int m = 0; m < 4; ++m) {
    #pragma unroll
    for (int j = 0; j < 4; ++j) {
      if (lq * 4 + j == lr) {               // diagonal of the 16x16 self frag
        sqld[w * 128 + m * 16 + lr]      = sa[m][j];
        sqld[w * 128 + 64 + m * 16 + lr] = sb[m][j];
      }
    }
  }
  __syncthreads();

  const float sg = sigma[0];
  const float inv = 0.5f / (sg * sg);
  float* oA = (float*)(smem + 65536);       // [32 i][64 j][8 f] f32 = 64 KB
  const size_t obase = (size_t)n * PC * PC * PF + (size_t)fg * 8;

  #pragma unroll
  for (int half = 0; half < 2; ++half) {
    // fill oA for il in [half*32, half*32+32): frags m = half*2, half*2+1
    #pragma unroll
    for (int mm = 0; mm < 2; ++mm) {
      int m = half * 2 + mm;
      #pragma unroll
      for (int j = 0; j < 4; ++j) {
        int il = m * 16 + lq * 4 + j;       // global-local A row
        int ilh = il & 31;
        float si = sqld[w * 128 + il];
        #pragma unroll
        for (int q = 0; q < 4; ++q) {
          int jl = q * 16 + lr;
          float sj = sqld[w * 128 + 64 + jl];
          float d2 = fmaxf(si + sj - 2.0f * acc[m][q][j], 0.0f);
          oA[(ilh * 64 + jl) * 8 + w] = __expf(-d2 * inv);
        }
      }
    }
    __syncthreads();
    // cooperative out-write: rows [i0+half*32,+32) x cols [j0,+64), 32B chunks
    for (int p = tid; p < 32 * 64; p += 512) {
      int il = p >> 6, jl = p & 63;
      float4 v0 = *(const float4*)(oA + (il * 64 + jl) * 8);
      float4 v1 = *(const float4*)(oA + (il * 64 + jl) * 8 + 4);
      size_t o = obase + ((size_t)(i0 + half * 32 + il) * PC + (j0 + jl)) * PF;
      *(float4*)(out + o) = v0;
      *(float4*)(out + o + 4) = v1;
    }
    if (tile == 1) {
      // mirror (Gram symmetric): out[n][j0+a][i0+half*32+b][f] = oA[b][a]
      for (int p = tid; p < 64 * 32; p += 512) {
        int a = p >> 5, b = p & 31;
        float4 v0 = *(const float4*)(oA + (b * 64 + a) * 8);
        float4 v1 = *(const float4*)(oA + (b * 64 + a) * 8 + 4);
        size_t o = obase + ((size_t)(j0 + a) * PC + (i0 + half * 32 + b)) * PF;
        *(float4*)(out + o) = v0;
        *(float4*)(out + o + 4) = v1;
      }
    }
    __syncthreads();                        // oA reused by next half
  }
}

// ===========================================================================
// FALLBACK path (verified rounds 2-4): pack -> gram -> unpermute
// ===========================================================================
__global__ __launch_bounds__(256) void pack_kernel(const float* __restrict__ x,
                                                   unsigned short* __restrict__ xt) {
  const int nc = blockIdx.x;
  const int n = nc >> 7, c = nc & 127;
  const float4* src4 = (const float4*)(x + (size_t)nc * (PT * PF));
  __shared__ unsigned short lds[32][522];
  const int tid = threadIdx.x;
  #pragma unroll
  for (int i = 0; i < 16; ++i) {
    int idx = i * 256 + tid;
    float4 v = src4[idx];
    int flat = idx << 2;
    int t = flat >> 5, f0 = flat & 31;
    lds[f0 + 0][t] = f2bf(v.x);
    lds[f0 + 1][t] = f2bf(v.y);
    lds[f0 + 2][t] = f2bf(v.z);
    lds[f0 + 3][t] = f2bf(v.w);
  }
  __syncthreads();
  #pragma unroll
  for (int i = 0; i < 16; ++i) {
    int idx = i * 256 + tid;
    int f = idx >> 7;
    int t4 = (idx & 127) << 2;
    ushort4 v;
    v.x = lds[f][t4 + 0];
    v.y = lds[f][t4 + 1];
    v.z = lds[f][t4 + 2];
    v.w = lds[f][t4 + 3];
    ushort4* dst = (ushort4*)(xt + (((size_t)(n * PF + f) * PC + c) * PT));
    dst[idx & 127] = v;
  }
}

__global__ __launch_bounds__(256) void gram_kernel(const unsigned short* __restrict__ xt,
                                                   const float* __restrict__ sigma,
                                                   float* __restrict__ dst) {
  const int b = blockIdx.x;
  const int n = b >> 5, f = b & 31;
  const unsigned short* A = xt + (size_t)b * PC * PT;
  __shared__ __align__(16) unsigned short lds[2][PC * 64];
  __shared__ float sq[PC];
  const int tid = threadIdx.x;
  const int wv = tid >> 6, ln = tid & 63;
  const int r0 = (wv >> 1) * 64, c0 = (wv & 1) * 64;
  const int lr = ln & 15, lq = ln >> 4;
  f32x4 acc[4][4];
  #pragma unroll
  for (int m = 0; m < 4; ++m)
    #pragma unroll
    for (int nn = 0; nn < 4; ++nn)
      acc[m][nn] = (f32x4){0.f, 0.f, 0.f, 0.f};
  const int srow = ln >> 3;
  const int sblk = (ln & 7) ^ srow;
  #pragma unroll
  for (int i = 0; i < 4; ++i) {
    int slot = i * 4 + wv;
    int crow = slot * 8 + srow;
    const unsigned short* g = A + (size_t)crow * PT + 0 + sblk * 8;
    __builtin_amdgcn_global_load_lds((gu32*)g, (lu32*)(&lds[0][slot * 512]), 16, 0, 0);
  }
  __syncthreads();
  for (int ks = 0; ks < 8; ++ks) {
    if (ks < 7) {
      const int t1 = (ks + 1) * 64;
      #pragma unroll
      for (int i = 0; i < 4; ++i) {
        int slot = i * 4 + wv;
        int crow = slot * 8 + srow;
        const unsigned short* g = A + (size_t)crow * PT + t1 + sblk * 8;
        __builtin_amdgcn_global_load_lds((gu32*)g, (lu32*)(&lds[(ks + 1) & 1][slot * 512]), 16, 0, 0);
      }
    }
    const unsigned short* L = lds[ks & 1];
    #pragma unroll
    for (int kk = 0; kk < 64; kk += 32) {
      bf16x8 av[4], bv[4];
      #pragma unroll
      for (int m = 0; m < 4; ++m) {
        int row = r0 + m * 16 + lr;
        av[m] = *(const bf16x8*)((const char*)L + row * 128 + ((((kk >> 3) + lq) ^ (row & 7)) << 4));
      }
      #pragma unroll
      for (int m = 0; m < 4; ++m) {
        int row = c0 + m * 16 + lr;
        bv[m] = *(const bf16x8*)((const char*)L + row * 128 + ((((kk >> 3) + lq) ^ (row & 7)) << 4));
      }
      #pragma unroll
      for (int m = 0; m < 4; ++m)
        #pragma unroll
        for (int nn = 0; nn < 4; ++nn)
          acc[m][nn] = __builtin_amdgcn_mfma_f32_16x16x32_bf16(av[m], bv[nn], acc[m][nn], 0, 0, 0);
    }
    __syncthreads();
  }
  #pragma unroll
  for (int m = 0; m < 4; ++m) {
    int rowb = r0 + m * 16 + lq * 4;
    int col  = c0 + m * 16 + lr;
    #pragma unroll
    for (int j = 0; j < 4; ++j)
      if (rowb + j == col) sq[col] = acc[m][m][j];
  }
  __syncthreads();
  const float sg = sigma[0];
  const float inv = 0.5f / (sg * sg);
  #pragma unroll
  for (int m = 0; m < 4; ++m) {
    #pragma unroll
    for (int nn = 0; nn < 4; ++nn) {
      int col = c0 + nn * 16 + lr;
      #pragma unroll
      for (int j = 0; j < 4; ++j) {
        int row = r0 + m * 16 + lq * 4 + j;
        float g = acc[m][nn][j];
        float d2 = fmaxf(sq[row] + sq[col] - 2.0f * g, 0.0f);
        ((float*)dst)[(size_t)n * (PC * PC * PF) + ((size_t)row * PC + col) * PF + f] = __expf(-d2 * inv);
      }
    }
  }
}

extern "C" void kernel_launch(void* const* d_in, const int* in_sizes, int n_in,
                              void* d_out, int out_size, void* d_ws, size_t ws_size,
                              hipStream_t stream) {
  const float* x = (const float*)d_in[0];
  const float* sigma = (const float*)d_in[1];
  float* out = (float*)d_out;

  hipError_t e = hipFuncSetAttribute((const void*)fused_kernel,
                                     hipFuncAttributeMaxDynamicSharedMemorySize, 131072);
  if (e == hipSuccess) {
    hipLaunchKernelGGL(fused_kernel, dim3(PN * 12), dim3(512), 131072, stream,
                       x, sigma, out);
  } else {
    // fallback: verified 3-stage path (gram writes final layout directly)
    unsigned short* xt = (unsigned short*)d_ws;
    hipLaunchKernelGGL(pack_kernel, dim3(PN * PC), dim3(256), 0, stream, x, xt);
    hipLaunchKernelGGL(gram_kernel, dim3(PN * PF), dim3(256), 0, stream, xt, sigma, out);
  }
}